// Round 9
// baseline (332.483 us; speedup 1.0000x reference)
//
#include <hip/hip_runtime.h>
#include <hip/hip_bf16.h>
#include <math.h>

#define H 128
#define BKT_SHIFT 9
#define BKT_NODES 512
#define CHUNK 2048   // edges per block in phase A/B
#define GEMM_GRID 512
#define FP8_SCALE 64.0f
#define FP8_INV (1.0f / 64.0f)

typedef __attribute__((ext_vector_type(8))) short short8;
typedef __attribute__((ext_vector_type(4))) float f32x4;
typedef __attribute__((ext_vector_type(2))) float f32x2;

static __device__ __forceinline__ ushort f2b(float v) {
    union { float f; unsigned u; } x; x.f = v;
    unsigned r = x.u + 0x7fffu + ((x.u >> 16) & 1u);
    return (ushort)(r >> 16);
}

// ---------------- Bucketed CSR build ----------------

__global__ void bucket_hist_kernel(const int* __restrict__ dst, int e,
                                   int* __restrict__ bucketCount, int* __restrict__ blockBase) {
    __shared__ int hist[256];
    int t = threadIdx.x;
    hist[t] = 0;
    __syncthreads();
    int base = blockIdx.x * CHUNK;
    #pragma unroll
    for (int k = 0; k < CHUNK / 256; k++) {
        int i = base + k * 256 + t;
        if (i < e) atomicAdd(&hist[dst[i] >> BKT_SHIFT], 1);
    }
    __syncthreads();
    blockBase[blockIdx.x * 256 + t] = atomicAdd(&bucketCount[t], hist[t]);
}

__global__ void bucket_scan_kernel(const int* __restrict__ bucketCount, int* __restrict__ bucketBase,
                                   int* __restrict__ rs, int n, int e) {
    if (threadIdx.x == 0 && blockIdx.x == 0) {
        int acc = 0;
        for (int i = 0; i < 256; i++) { bucketBase[i] = acc; acc += bucketCount[i]; }
        bucketBase[256] = acc;
        rs[n] = e;
    }
}

__global__ void bucket_scatter_kernel(const int* __restrict__ src, const int* __restrict__ dst, int e,
                                      const int* __restrict__ bucketBase, const int* __restrict__ blockBase,
                                      int2* __restrict__ grouped) {
    __shared__ int cur[256];
    int t = threadIdx.x;
    cur[t] = bucketBase[t] + blockBase[blockIdx.x * 256 + t];
    __syncthreads();
    int base = blockIdx.x * CHUNK;
    #pragma unroll
    for (int k = 0; k < CHUNK / 256; k++) {
        int i = base + k * 256 + t;
        if (i < e) {
            int d = dst[i];
            int pos = atomicAdd(&cur[d >> BKT_SHIFT], 1);
            int2 p; p.x = d; p.y = src[i];
            grouped[pos] = p;
        }
    }
}

__global__ void bucket_csr_kernel(const int2* __restrict__ grouped, const int* __restrict__ bucketBase,
                                  int* __restrict__ rs, int* __restrict__ csr, int n) {
    __shared__ int sdeg[BKT_NODES];
    __shared__ int sexcl[BKT_NODES];
    __shared__ int wsum[4];
    int b = blockIdx.x;
    int t = threadIdx.x;
    int nodeBase = b << BKT_SHIFT;
    int ebase = bucketBase[b], eend = bucketBase[b + 1];
    sdeg[t] = 0; sdeg[t + 256] = 0;
    __syncthreads();
    for (int e = ebase + t; e < eend; e += 256)
        atomicAdd(&sdeg[grouped[e].x - nodeBase], 1);
    __syncthreads();
    int lane = t & 63, wid = t >> 6;
    int v0 = sdeg[2 * t], v1 = sdeg[2 * t + 1];
    int p = v0 + v1;
    int x = p;
    #pragma unroll
    for (int off = 1; off < 64; off <<= 1) {
        int y = __shfl_up(x, off, 64);
        if (lane >= off) x += y;
    }
    if (lane == 63) wsum[wid] = x;
    __syncthreads();
    if (t == 0) {
        int acc = 0;
        #pragma unroll
        for (int w = 0; w < 4; w++) { int tmp = wsum[w]; wsum[w] = acc; acc += tmp; }
    }
    __syncthreads();
    int basep = wsum[wid] + x - p;
    sexcl[2 * t] = basep;
    sexcl[2 * t + 1] = basep + v0;
    int nodes = min(BKT_NODES, n - nodeBase);
    for (int i = t; i < nodes; i += 256) rs[nodeBase + i] = ebase + sexcl[i];
    sdeg[t] = 0; sdeg[t + 256] = 0;
    __syncthreads();
    for (int e = ebase + t; e < eend; e += 256) {
        int2 pr = grouped[e];
        int l = pr.x - nodeBase;
        int r = atomicAdd(&sdeg[l], 1);
        csr[ebase + sexcl[l] + r] = pr.y;
    }
}

// ---------------- Weight prep: Btg[layer][col][k] bf16, k<128 Wl, k>=128 Wr ----------------

__global__ void prep_w_kernel(const float* __restrict__ Wl, const float* __restrict__ Wr,
                              ushort* __restrict__ Btg) {
    int idx = blockIdx.x * 256 + threadIdx.x;   // 2*128*256 = 65536
    if (idx >= 65536) return;
    int l = idx >> 15;
    int col = (idx >> 8) & 127;
    int k = idx & 255;
    float v = (k < 128) ? Wl[l * H * H + k * H + col] : Wr[l * H * H + (k - 128) * H + col];
    Btg[idx] = f2b(v);
}

// ---------------- Layer 0 (in_dim = 1) ----------------

__global__ void agg0_kernel(const float* __restrict__ x, const int* __restrict__ rs,
                            const int* __restrict__ csr, float* __restrict__ agg0, int n) {
    int i = blockIdx.x * 256 + threadIdx.x;
    if (i >= n) return;
    int a = rs[i], b = rs[i + 1];
    float s = 0.f;
    for (int e = a; e < b; e++) s += x[csr[e]];
    agg0[i] = s / (float)max(b - a, 1);
}

// thread = (node, plane): 16 features -> bf16 row-major + fp8 plane-major (scaled)
__global__ void expand0_kernel(const float* __restrict__ x, const float* __restrict__ agg0,
                               const float* __restrict__ Wl0, const float* __restrict__ bl0,
                               const float* __restrict__ Wr0, ushort* __restrict__ hout,
                               unsigned char* __restrict__ h8, int n) {
    int idx = blockIdx.x * 256 + threadIdx.x;   // over N*8
    if (idx >= n * 8) return;
    int i = idx >> 3, p = idx & 7;
    float gi = agg0[i], xi = x[i];
    float v[16];
    #pragma unroll
    for (int k = 0; k < 16; k++) {
        int f = p * 16 + k;
        v[k] = fmaxf(gi * Wl0[f] + bl0[f] + xi * Wr0[f], 0.f);
    }
    short8 o0, o1;
    #pragma unroll
    for (int k = 0; k < 8; k++) { o0[k] = (short)f2b(v[k]); o1[k] = (short)f2b(v[k + 8]); }
    ushort* hp = hout + (size_t)i * H + p * 16;
    *(short8*)hp = o0;
    *(short8*)(hp + 8) = o1;
    uint4 u;
    unsigned* up = (unsigned*)&u;
    #pragma unroll
    for (int d = 0; d < 4; d++) {
        int pk = __builtin_amdgcn_cvt_pk_fp8_f32(v[4 * d] * FP8_SCALE, v[4 * d + 1] * FP8_SCALE, 0, false);
        pk = __builtin_amdgcn_cvt_pk_fp8_f32(v[4 * d + 2] * FP8_SCALE, v[4 * d + 3] * FP8_SCALE, pk, true);
        up[d] = (unsigned)pk;
    }
    *(uint4*)(h8 + ((size_t)p * n + i) * 16) = u;
}

// ---------------- Plane-partitioned aggregate (XCD-local gather) ----------------
// plane = blockIdx & 7 -> one 1.6 MB feature plane per XCD L2 (de-facto %8 mapping).
// One thread per (node, plane): serial edge loop, 16 B gather/edge, private f32 accum.

__global__ void aggregate_p_kernel(const unsigned char* __restrict__ h8, const int* __restrict__ rs,
                                   const int* __restrict__ csr, ushort* __restrict__ aggp, int n) {
    int p = blockIdx.x & 7;
    int node = (blockIdx.x >> 3) * 256 + threadIdx.x;
    if (node >= n) return;
    const unsigned char* plane = h8 + (size_t)p * n * 16;
    int a = rs[node], b = rs[node + 1];
    f32x2 s[8];
    #pragma unroll
    for (int j = 0; j < 8; j++) s[j] = (f32x2){0.f, 0.f};
    int e = a;
    for (; e + 2 <= b; e += 2) {
        int n0 = csr[e], n1 = csr[e + 1];
        uint4 u0 = *(const uint4*)(plane + (size_t)n0 * 16);
        uint4 u1 = *(const uint4*)(plane + (size_t)n1 * 16);
        unsigned d0[4] = {u0.x, u0.y, u0.z, u0.w};
        unsigned d1[4] = {u1.x, u1.y, u1.z, u1.w};
        #pragma unroll
        for (int d = 0; d < 4; d++) {
            s[2 * d]     += __builtin_amdgcn_cvt_pk_f32_fp8(d0[d], false);
            s[2 * d + 1] += __builtin_amdgcn_cvt_pk_f32_fp8(d0[d], true);
            s[2 * d]     += __builtin_amdgcn_cvt_pk_f32_fp8(d1[d], false);
            s[2 * d + 1] += __builtin_amdgcn_cvt_pk_f32_fp8(d1[d], true);
        }
    }
    if (e < b) {
        int n0 = csr[e];
        uint4 u0 = *(const uint4*)(plane + (size_t)n0 * 16);
        unsigned d0[4] = {u0.x, u0.y, u0.z, u0.w};
        #pragma unroll
        for (int d = 0; d < 4; d++) {
            s[2 * d]     += __builtin_amdgcn_cvt_pk_f32_fp8(d0[d], false);
            s[2 * d + 1] += __builtin_amdgcn_cvt_pk_f32_fp8(d0[d], true);
        }
    }
    float inv = FP8_INV / (float)max(b - a, 1);
    // feature k (0..15): lives in s[(k>>2)*2 + ((k>>1)&1)][k&1]
    short8 o0, o1;
    #pragma unroll
    for (int d = 0; d < 2; d++) {
        o0[4 * d]     = (short)f2b(s[2 * d].x * inv);
        o0[4 * d + 1] = (short)f2b(s[2 * d].y * inv);
        o0[4 * d + 2] = (short)f2b(s[2 * d + 1].x * inv);
        o0[4 * d + 3] = (short)f2b(s[2 * d + 1].y * inv);
        o1[4 * d]     = (short)f2b(s[2 * d + 4].x * inv);
        o1[4 * d + 1] = (short)f2b(s[2 * d + 4].y * inv);
        o1[4 * d + 2] = (short)f2b(s[2 * d + 5].x * inv);
        o1[4 * d + 3] = (short)f2b(s[2 * d + 5].y * inv);
    }
    ushort* dstp = aggp + ((size_t)p * n + node) * 16;
    *(short8*)dstp = o0;
    *(short8*)(dstp + 8) = o1;
}

// ---------------- Fused dual GEMM, B in registers, transposed MFMA output ----------------
// A: agg half from plane-major bf16 (aggp), root half from row-major bf16 (hb).
// POOL=false: store bf16 rows + fp8 plane-major shadow. POOL=true: feature sums.

template<bool POOL>
__global__ __launch_bounds__(256, 2) void gemm_kernel(
    const ushort* __restrict__ aggp, const ushort* __restrict__ hb,
    const ushort* __restrict__ Btg,   // [128][256] bf16 for this layer
    const float* __restrict__ bias, ushort* __restrict__ out,
    unsigned char* __restrict__ out8,
    float* __restrict__ partial, int nblk, int n) {
    __shared__ float sums[2][128];
    int tid = threadIdx.x;
    int wave = tid >> 6, lane = tid & 63;
    int l15 = lane & 15, lhi = lane >> 4;
    int colhalf = wave & 1;
    int rowsub = wave >> 1;
    int colbase = colhalf * 64;

    short8 bf[4][8];
    #pragma unroll
    for (int c2 = 0; c2 < 4; c2++) {
        const ushort* wp = Btg + (colbase + c2 * 16 + l15) * 256 + lhi * 8;
        #pragma unroll
        for (int s = 0; s < 8; s++)
            bf[c2][s] = *(const short8*)(wp + s * 32);
    }
    f32x4 bias_v[4];
    #pragma unroll
    for (int c2 = 0; c2 < 4; c2++)
        bias_v[c2] = *(const f32x4*)(bias + colbase + c2 * 16 + lhi * 4);

    f32x4 fs[4];
    #pragma unroll
    for (int c2 = 0; c2 < 4; c2++) fs[c2] = (f32x4){0.f, 0.f, 0.f, 0.f};

    for (int r0 = blockIdx.x * 32; r0 < n; r0 += nblk * 32) {
        int row = r0 + rowsub * 16 + l15;
        int arow = min(row, n - 1);
        short8 af[8];
        #pragma unroll
        for (int s = 0; s < 4; s++) {
            int f0 = s * 32 + lhi * 8;
            af[s] = *(const short8*)(aggp + ((size_t)(f0 >> 4) * n + arow) * 16 + (f0 & 15));
        }
        #pragma unroll
        for (int s = 4; s < 8; s++)
            af[s] = *(const short8*)(hb + (size_t)arow * H + (s & 3) * 32 + lhi * 8);
        f32x4 acc[4];
        #pragma unroll
        for (int c2 = 0; c2 < 4; c2++) acc[c2] = (f32x4){0.f, 0.f, 0.f, 0.f};
        #pragma unroll
        for (int s = 0; s < 8; s++) {
            #pragma unroll
            for (int c2 = 0; c2 < 4; c2++)
                acc[c2] = __builtin_amdgcn_mfma_f32_16x16x32_bf16(bf[c2][s], af[s], acc[c2], 0, 0, 0);
        }
        if (row < n) {
            if (POOL) {
                #pragma unroll
                for (int c2 = 0; c2 < 4; c2++)
                    #pragma unroll
                    for (int r = 0; r < 4; r++)
                        fs[c2][r] += fmaxf(acc[c2][r] + bias_v[c2][r], 0.f);
            } else {
                #pragma unroll
                for (int c2 = 0; c2 < 4; c2++) {
                    float v0 = fmaxf(acc[c2][0] + bias_v[c2][0], 0.f);
                    float v1 = fmaxf(acc[c2][1] + bias_v[c2][1], 0.f);
                    float v2 = fmaxf(acc[c2][2] + bias_v[c2][2], 0.f);
                    float v3 = fmaxf(acc[c2][3] + bias_v[c2][3], 0.f);
                    ushort4 o;
                    o.x = f2b(v0); o.y = f2b(v1); o.z = f2b(v2); o.w = f2b(v3);
                    *(ushort4*)(out + (size_t)row * H + colbase + c2 * 16 + lhi * 4) = o;
                    int pk = __builtin_amdgcn_cvt_pk_fp8_f32(v0 * FP8_SCALE, v1 * FP8_SCALE, 0, false);
                    pk = __builtin_amdgcn_cvt_pk_fp8_f32(v2 * FP8_SCALE, v3 * FP8_SCALE, pk, true);
                    int pl = colhalf * 4 + c2;
                    *(unsigned*)(out8 + ((size_t)pl * n + row) * 16 + lhi * 4) = (unsigned)pk;
                }
            }
        }
    }

    if (POOL) {
        #pragma unroll
        for (int c2 = 0; c2 < 4; c2++) {
            #pragma unroll
            for (int m = 1; m < 16; m <<= 1) {
                #pragma unroll
                for (int r = 0; r < 4; r++)
                    fs[c2][r] += __shfl_xor(fs[c2][r], m, 64);
            }
        }
        if (l15 == 0) {
            #pragma unroll
            for (int c2 = 0; c2 < 4; c2++)
                #pragma unroll
                for (int r = 0; r < 4; r++)
                    sums[rowsub][colbase + c2 * 16 + lhi * 4 + r] = fs[c2][r];
        }
        __syncthreads();
        if (tid < 128)
            partial[tid * nblk + blockIdx.x] = sums[0][tid] + sums[1][tid];
    }
}

// ---------------- Final pooling reduce: one wave per feature ----------------

__global__ void pool_reduce_kernel(const float* __restrict__ partial, float* __restrict__ pooled,
                                   int nb, float invn) {
    int j = blockIdx.x;
    int t = threadIdx.x;     // 64
    float s = 0.f;
    for (int b = t; b < nb; b += 64) s += partial[j * nb + b];
    #pragma unroll
    for (int off = 32; off > 0; off >>= 1) s += __shfl_down(s, off, 64);
    if (t == 0) pooled[j] = s * invn;
}

// ---------------- Final MLP ----------------

__global__ void mlp_kernel(const float* __restrict__ pooled,
                           const float* __restrict__ Wv, const float* __restrict__ bv,
                           const float* __restrict__ temp, const float* __restrict__ tt,
                           const float* __restrict__ Wm1, const float* __restrict__ bm1,
                           const float* __restrict__ Wm2, const float* __restrict__ bm2,
                           float* __restrict__ out) {
    __shared__ float feat[66];
    __shared__ float red[2];
    int j = threadIdx.x;  // 128 threads
    if (j < 64) {
        float s = bv[j];
        for (int k = 0; k < H; k++) s += pooled[k] * Wv[k * 64 + j];
        feat[j] = s;
    }
    if (j == 64) feat[64] = temp[0];
    if (j == 65) feat[65] = tt[0];
    __syncthreads();
    float m = bm1[j];
    for (int k = 0; k < 66; k++) m += feat[k] * Wm1[k * H + j];
    m = fmaxf(m, 0.f);
    float p = m * Wm2[j];
    #pragma unroll
    for (int off = 32; off > 0; off >>= 1) p += __shfl_down(p, off, 64);
    if ((j & 63) == 0) red[j >> 6] = p;
    __syncthreads();
    if (j == 0) {
        float x = red[0] + red[1] + bm2[0];
        out[0] = (x > 20.f) ? x : log1pf(expf(x));
    }
}

// ---------------- Launch ----------------

extern "C" void kernel_launch(void* const* d_in, const int* in_sizes, int n_in,
                              void* d_out, int out_size, void* d_ws, size_t ws_size,
                              hipStream_t stream) {
    const float* node_feats = (const float*)d_in[0];
    const int* edge_index = (const int*)d_in[1];
    const float* temp = (const float*)d_in[3];
    const float* tt   = (const float*)d_in[4];
    const float* Wl0 = (const float*)d_in[5];
    const float* bl0 = (const float*)d_in[6];
    const float* Wr0 = (const float*)d_in[7];
    const float* Wl  = (const float*)d_in[8];
    const float* bl  = (const float*)d_in[9];
    const float* Wr  = (const float*)d_in[10];
    const float* Wv  = (const float*)d_in[11];
    const float* bv  = (const float*)d_in[12];
    const float* Wm1 = (const float*)d_in[13];
    const float* bm1 = (const float*)d_in[14];
    const float* Wm2 = (const float*)d_in[15];
    const float* bm2 = (const float*)d_in[16];

    const int N = in_sizes[0];
    const int E = in_sizes[1] / 2;
    const int* src = edge_index;
    const int* dst = edge_index + E;

    size_t NH = (size_t)N * H;
    ushort* hA   = (ushort*)d_ws;            // N*H bf16 (row-major)
    ushort* hB   = hA + NH;                  // N*H bf16 (row-major)
    ushort* aggp = hB + NH;                  // N*H bf16 (plane-major [8][N][16])
    ushort* Btg  = aggp + NH;                // 2*128*256 bf16
    float* agg0  = (float*)(Btg + 65536);    // N f32
    int2* grouped = (int2*)(agg0 + N);       // E pairs (dead after CSR build)
    int* csr     = (int*)(grouped + E);      // E
    int* rs      = csr + E;                  // N+1
    int* bucketCount = rs + (N + 1);         // 256
    int* bucketBase  = bucketCount + 256;    // 257
    int* blockBase   = bucketBase + 257;     // NBLK*256
    int NBLK = (E + CHUNK - 1) / CHUNK;
    float* partial = (float*)(blockBase + NBLK * 256);  // H*GEMM_GRID
    float* pooled  = partial + (size_t)H * GEMM_GRID;   // H
    unsigned char* hB8 = (unsigned char*)(pooled + H);  // [8][N][16] fp8
    unsigned char* hA8 = (unsigned char*)grouped;       // [8][N][16] fp8, aliases dead 'grouped'

    int NB = (N + BKT_NODES - 1) / BKT_NODES;

    // CSR build (bucketed)
    hipMemsetAsync(bucketCount, 0, 256 * sizeof(int), stream);
    bucket_hist_kernel<<<NBLK, 256, 0, stream>>>(dst, E, bucketCount, blockBase);
    bucket_scan_kernel<<<1, 64, 0, stream>>>(bucketCount, bucketBase, rs, N, E);
    bucket_scatter_kernel<<<NBLK, 256, 0, stream>>>(src, dst, E, bucketBase, blockBase, grouped);
    bucket_csr_kernel<<<NB, 256, 0, stream>>>(grouped, bucketBase, rs, csr, N);

    // Weights -> bf16 transposed [layer][col][k]
    prep_w_kernel<<<256, 256, 0, stream>>>(Wl, Wr, Btg);

    // Layer 0 scalar part -> hA (bf16 rows) + hA8 (fp8 planes; grouped is dead by now)
    agg0_kernel<<<(N + 255) / 256, 256, 0, stream>>>(node_feats, rs, csr, agg0, N);
    expand0_kernel<<<((size_t)N * 8 + 255) / 256, 256, 0, stream>>>(
        node_feats, agg0, Wl0, bl0, Wr0, hA, hA8, N);

    int AGG_GRID = ((N + 255) / 256) * 8;

    // Layer 1: plane-local fp8 gather-mean on hA8 -> gemm -> hB (+ hB8 planes)
    aggregate_p_kernel<<<AGG_GRID, 256, 0, stream>>>(hA8, rs, csr, aggp, N);
    gemm_kernel<false><<<GEMM_GRID, 256, 0, stream>>>(aggp, hA, Btg, bl, hB, hB8, nullptr, GEMM_GRID, N);

    // Layer 2: plane-local fp8 gather-mean on hB8 -> gemm (fused pooling)
    aggregate_p_kernel<<<AGG_GRID, 256, 0, stream>>>(hB8, rs, csr, aggp, N);
    gemm_kernel<true><<<GEMM_GRID, 256, 0, stream>>>(aggp, hB, Btg + 32768, bl + H, nullptr, nullptr, partial, GEMM_GRID, N);

    // Final pooling reduce + MLP
    pool_reduce_kernel<<<H, 64, 0, stream>>>(partial, pooled, GEMM_GRID, 1.0f / (float)N);
    mlp_kernel<<<1, H, 0, stream>>>(pooled, Wv, bv, temp, tt, Wm1, bm1, Wm2, bm2, (float*)d_out);
}